// Round 1
// 80.913 us; speedup vs baseline: 1.0602x; 1.0602x over previous
//
#include <hip/hip_runtime.h>

// FVNet: B=8, F=512, N=512, K=32, fp32.
// Round 5: fuse k_ax + k_fv into k_axfv by removing the n-split across
// blocks. Each k_axfv block owns ALL n=512 for an 8-f tile, so the fv
// epilogue (which only reduces over k=32 per (b,f)) runs in the same
// kernel: no axP/ax2P partial round-trip (16.8 MB), one fewer dispatch.
// Grid 512 blocks = 2 blocks/CU (8 waves/CU) vs k_ax's 1/CU.
// k_a unchanged from R4 (verified).
//
// Per-b global l2norm == 1/sqrt(512) analytically: all 512 K-rows are
// unit-norm after the first normalization and row norms are O(10), never
// near the 1e-12 clamp.
// ws floats: aP[131072] | asumP[8192]

#define B_ 8
#define F_ 512
#define N_ 512
#define K_ 32

// ---------------- K1: logits + softmax + a + asumP ----------------
// grid = B * 32 ntiles (16 n) = 256 blocks, 256 threads.
// Threads: fs = t>>4 (16-way f-split), kg = (t>>2)&3 (8 k), ng = t&3 (4 n).
__global__ __launch_bounds__(256) void k_a(const float* __restrict__ x,
                                           const float* __restrict__ W,
                                           const float* __restrict__ bias,
                                           float* __restrict__ aP,
                                           float* __restrict__ asumP) {
  __shared__ float xs[128][18];     // [f][n], mild conflicts only
  __shared__ float ws[128 * 32];    // [f][k ^ (f&31)] XOR-swizzled, no pad
  __shared__ float red2[16][516];   // [fs][row*32+k] partial dump
  __shared__ float sm4[4][32];      // per-wave asum partials
  const int t = threadIdx.x;
  const int b  = blockIdx.x >> 5;
  const int nt = blockIdx.x & 31;
  const int n0 = nt << 4;
  const int ng = t & 3;
  const int kg = (t >> 2) & 3;
  const int fs = t >> 4;
  const int n4 = ng * 4;
  const int k8 = kg * 8;

  float acc[4][8];
#pragma unroll
  for (int i = 0; i < 4; ++i)
#pragma unroll
    for (int j = 0; j < 8; ++j) acc[i][j] = 0.f;

  float xr[8], wr[16];
  // ---- prefetch + store phase 0 ----
#pragma unroll
  for (int it = 0; it < 8; ++it) {
    int flat = t + 256 * it;
    xr[it] = x[(size_t)(b * F_ + (flat >> 4)) * N_ + n0 + (flat & 15)];
  }
#pragma unroll
  for (int it = 0; it < 16; ++it) {
    int flat = t + 256 * it;
    wr[it] = W[(flat >> 7) * F_ + (flat & 127)];
  }
#pragma unroll
  for (int it = 0; it < 8; ++it) {
    int flat = t + 256 * it;
    xs[flat >> 4][flat & 15] = xr[it];
  }
#pragma unroll
  for (int it = 0; it < 16; ++it) {
    int flat = t + 256 * it;
    int f = flat & 127, k = flat >> 7;
    ws[f * 32 + (k ^ (f & 31))] = wr[it];
  }
  __syncthreads();

  for (int ph = 0; ph < 4; ++ph) {
    if (ph < 3) {   // prefetch next phase into registers
      const int fb = (ph + 1) << 7;
#pragma unroll
      for (int it = 0; it < 8; ++it) {
        int flat = t + 256 * it;
        xr[it] = x[(size_t)(b * F_ + fb + (flat >> 4)) * N_ + n0 + (flat & 15)];
      }
#pragma unroll
      for (int it = 0; it < 16; ++it) {
        int flat = t + 256 * it;
        wr[it] = W[(flat >> 7) * F_ + fb + (flat & 127)];
      }
    }
#pragma unroll
    for (int fi = 0; fi < 8; ++fi) {
      const int f = fs * 8 + fi;
      const float2 x01 = *(const float2*)&xs[f][n4];
      const float2 x23 = *(const float2*)&xs[f][n4 + 2];
      const float4 wA = *(const float4*)&ws[f * 32 + ((k8) ^ (f & 28))];
      const float4 wB = *(const float4*)&ws[f * 32 + ((k8 + 4) ^ (f & 28))];
      const float xv[4] = {x01.x, x01.y, x23.x, x23.y};
      const float wa[4] = {((const float*)&wA)[0 ^ (fi & 3)],
                           ((const float*)&wA)[1 ^ (fi & 3)],
                           ((const float*)&wA)[2 ^ (fi & 3)],
                           ((const float*)&wA)[3 ^ (fi & 3)]};
      const float wb[4] = {((const float*)&wB)[0 ^ (fi & 3)],
                           ((const float*)&wB)[1 ^ (fi & 3)],
                           ((const float*)&wB)[2 ^ (fi & 3)],
                           ((const float*)&wB)[3 ^ (fi & 3)]};
#pragma unroll
      for (int i = 0; i < 4; ++i)
#pragma unroll
        for (int j = 0; j < 4; ++j) {
          acc[i][j]     += xv[i] * wa[j];
          acc[i][4 + j] += xv[i] * wb[j];
        }
    }
    __syncthreads();
    if (ph < 3) {
#pragma unroll
      for (int it = 0; it < 8; ++it) {
        int flat = t + 256 * it;
        xs[flat >> 4][flat & 15] = xr[it];
      }
#pragma unroll
      for (int it = 0; it < 16; ++it) {
        int flat = t + 256 * it;
        int f = flat & 127, k = flat >> 7;
        ws[f * 32 + (k ^ (f & 31))] = wr[it];
      }
      __syncthreads();
    }
  }

  // ---- dump partials ----
#pragma unroll
  for (int i = 0; i < 4; ++i) {
    float4 v1, v2;
    v1.x = acc[i][0]; v1.y = acc[i][1]; v1.z = acc[i][2]; v1.w = acc[i][3];
    v2.x = acc[i][4]; v2.y = acc[i][5]; v2.z = acc[i][6]; v2.w = acc[i][7];
    *(float4*)&red2[fs][(n4 + i) * 32 + k8] = v1;
    *(float4*)&red2[fs][(n4 + i) * 32 + k8 + 4] = v2;
  }
  __syncthreads();

  // ---- combine 16 f-splits; thread owns outputs o0=2t, o0+1 ----
  const int o0 = 2 * t;
  const int row = t >> 4;        // n within tile
  const int k0 = o0 & 31;
  float l0 = bias[k0], l1 = bias[k0 + 1];
#pragma unroll
  for (int s2 = 0; s2 < 16; ++s2) {
    float2 r = *(const float2*)&red2[s2][o0];
    l0 += r.x; l1 += r.y;
  }
  // ---- softmax over 32 k (16-lane group shuffles) ----
  float m = fmaxf(l0, l1);
  m = fmaxf(m, __shfl_xor(m, 1));
  m = fmaxf(m, __shfl_xor(m, 2));
  m = fmaxf(m, __shfl_xor(m, 4));
  m = fmaxf(m, __shfl_xor(m, 8));
  const float e0 = __expf(l0 - m), e1 = __expf(l1 - m);
  float ssum = e0 + e1;
  ssum += __shfl_xor(ssum, 1);
  ssum += __shfl_xor(ssum, 2);
  ssum += __shfl_xor(ssum, 4);
  ssum += __shfl_xor(ssum, 8);
  const float inv = 1.f / ssum;
  const float a0 = e0 * inv, a1 = e1 * inv;
  float2 av; av.x = a0; av.y = a1;
  *(float2*)&aP[(size_t)(b * N_ + n0 + row) * K_ + k0] = av;

  // ---- asum partials over the 16 rows ----
  float s0 = a0 + __shfl_xor(a0, 16); s0 += __shfl_xor(s0, 32);
  float s1 = a1 + __shfl_xor(a1, 16); s1 += __shfl_xor(s1, 32);
  const int l = t & 63, w = t >> 6;
  if (l < 16) { sm4[w][2 * l] = s0; sm4[w][2 * l + 1] = s1; }
  __syncthreads();
  if (t < 32) {
    float tot = sm4[0][t] + sm4[1][t] + sm4[2][t] + sm4[3][t];
    asumP[(b * 32 + nt) * 32 + t] = tot;
  }
}

// ---------------- K2: ax/ax2 GEMMs + fv epilogue (fused) ----------------
// grid = B * 64 ftiles (8 f) = 512 blocks (2 blocks/CU), 256 threads.
// Main loop threads: ns = t>>4 (16-way n-split), fg = (t>>3)&1 (4 f),
// kg = t&7 (4 k); 32 accumulators/thread over 32 n each (4 chunks x 8).
// Epilogue: LDS-reduce the 16 ns-partials, fv math, 32-lane k-norm, store.
__global__ __launch_bounds__(256) void k_axfv(const float* __restrict__ x,
                                              const float* __restrict__ aP,
                                              const float* __restrict__ asumP,
                                              const float* __restrict__ mu,
                                              const float* __restrict__ sg,
                                              float* __restrict__ out) {
  // pool aliases: main loop {xs [8][132] | as_ [128][32]} = 5152 floats;
  // epilogue {red_ax 16x264 | red_bx 16x264} = 8448 floats.
  __shared__ float pool[8448];
  __shared__ float sm[32];
  float* xs  = pool;          // stride 132: conflict-free writes, 2-way reads
  float* as_ = pool + 1056;   // [n][k] linear: coalesced + conflict-free
  const int t  = threadIdx.x;
  const int b  = blockIdx.x >> 6;
  const int ft = blockIdx.x & 63;
  const int f0 = ft << 3;
  const int kg = t & 7;
  const int fg = (t >> 3) & 1;
  const int ns = t >> 4;
  const int k4 = kg * 4;
  const int f4 = fg * 4;

  // block-wide asum[b][k] from k_a's 32 n-tile partials
  if (t < 32) {
    float s = 0.f;
#pragma unroll
    for (int nt = 0; nt < 32; ++nt) s += asumP[(b * 32 + nt) * 32 + t];
    sm[t] = s;
  }

  float ax[4][4] = {{0.f}}, bx[4][4] = {{0.f}};
  float xr[4], ar[16];
  // ---- prefetch + store chunk 0 (n = 0..127) ----
#pragma unroll
  for (int it = 0; it < 4; ++it) {
    int flat = t + 256 * it;
    xr[it] = x[(size_t)(b * F_ + f0 + (flat >> 7)) * N_ + (flat & 127)];
  }
#pragma unroll
  for (int it = 0; it < 16; ++it)
    ar[it] = aP[(size_t)b * N_ * K_ + t + 256 * it];
#pragma unroll
  for (int it = 0; it < 4; ++it) {
    int flat = t + 256 * it;
    xs[(flat >> 7) * 132 + (flat & 127)] = xr[it];
  }
#pragma unroll
  for (int it = 0; it < 16; ++it) as_[t + 256 * it] = ar[it];
  __syncthreads();

  for (int c = 0; c < 4; ++c) {
    if (c < 3) {   // prefetch next 128-n chunk into registers
      const int nc = (c + 1) << 7;
#pragma unroll
      for (int it = 0; it < 4; ++it) {
        int flat = t + 256 * it;
        xr[it] = x[(size_t)(b * F_ + f0 + (flat >> 7)) * N_ + nc + (flat & 127)];
      }
#pragma unroll
      for (int it = 0; it < 16; ++it)
        ar[it] = aP[(size_t)b * N_ * K_ + nc * K_ + t + 256 * it];
    }
#pragma unroll
    for (int u = 0; u < 8; ++u) {
      const int n = ns * 8 + u;
      const float4 av = *(const float4*)&as_[n * 32 + k4];
      const float* ap = (const float*)&av;
      float xv[4];
#pragma unroll
      for (int i = 0; i < 4; ++i) xv[i] = xs[(f4 + i) * 132 + n];
#pragma unroll
      for (int i = 0; i < 4; ++i) {
        const float xi = xv[i];
        const float xq = xi * xi;
#pragma unroll
        for (int j = 0; j < 4; ++j) {
          ax[i][j] += xi * ap[j];
          bx[i][j] += xq * ap[j];
        }
      }
    }
    __syncthreads();
    if (c < 3) {
#pragma unroll
      for (int it = 0; it < 4; ++it) {
        int flat = t + 256 * it;
        xs[(flat >> 7) * 132 + (flat & 127)] = xr[it];
      }
#pragma unroll
      for (int it = 0; it < 16; ++it) as_[t + 256 * it] = ar[it];
      __syncthreads();
    }
  }

  // ---- dump ns-partials (pool is free after the last sync) ----
  // plane stride 264 (mod 32 = 8 banks) staggers the 4 ns-groups per wave
#pragma unroll
  for (int i = 0; i < 4; ++i) {
    float4 v1, v2;
    v1.x = ax[i][0]; v1.y = ax[i][1]; v1.z = ax[i][2]; v1.w = ax[i][3];
    v2.x = bx[i][0]; v2.y = bx[i][1]; v2.z = bx[i][2]; v2.w = bx[i][3];
    *(float4*)&pool[ns * 264 + (f4 + i) * 32 + k4] = v1;
    *(float4*)&pool[4224 + ns * 264 + (f4 + i) * 32 + k4] = v2;
  }
  __syncthreads();

  // ---- reduce 16 splits; thread owns (f = t>>5, k = t&31) ----
  const int fr = t >> 5;
  const int kr = t & 31;
  float axv = 0.f, a2v = 0.f;
#pragma unroll
  for (int p = 0; p < 16; ++p) {
    axv += pool[p * 264 + fr * 32 + kr];
    a2v += pool[4224 + p * 264 + fr * 32 + kr];
  }
  const float m  = mu[(f0 + fr) * K_ + kr];
  const float sd = sg[(f0 + fr) * K_ + kr];
  const float as = sm[kr];

  const float fv1 = (axv - m * as) / sd;
  const float fv2 = (a2v - 2.f * m * axv + m * m * as) / (sd * sd) - as;

  float s1 = fv1 * fv1, s2 = fv2 * fv2;
#pragma unroll
  for (int off = 16; off >= 1; off >>= 1) {
    s1 += __shfl_xor(s1, off, 32);
    s2 += __shfl_xor(s2, off, 32);
  }
  const float inv512 = 0.04419417382415922f;  // 1/sqrt(512)
  const float o1 = fv1 / fmaxf(sqrtf(s1), 1e-12f) * inv512;
  const float o2 = fv2 / fmaxf(sqrtf(s2), 1e-12f) * inv512;

  out[(size_t)b * (2 * F_ * K_) + (f0 + fr) * K_ + kr] = o1;
  out[(size_t)b * (2 * F_ * K_) + F_ * K_ + (f0 + fr) * K_ + kr] = o2;
}

extern "C" void kernel_launch(void* const* d_in, const int* in_sizes, int n_in,
                              void* d_out, int out_size, void* d_ws, size_t ws_size,
                              hipStream_t stream) {
  const float* x  = (const float*)d_in[0];
  const float* W  = (const float*)d_in[1];
  const float* bv = (const float*)d_in[2];
  const float* mu = (const float*)d_in[3];
  const float* sg = (const float*)d_in[4];
  float* out = (float*)d_out;

  float* ws    = (float*)d_ws;
  float* aP    = ws;                // 131072 floats
  float* asumP = ws + 131072;       // 8192 floats

  hipLaunchKernelGGL(k_a,    dim3(256), dim3(256), 0, stream, x, W, bv, aP, asumP);
  hipLaunchKernelGGL(k_axfv, dim3(512), dim3(256), 0, stream,
                     x, aP, asumP, mu, sg, out);
}